// Round 2
// baseline (872.416 us; speedup 1.0000x reference)
//
#include <hip/hip_runtime.h>
#include <hip/hip_bf16.h>

// Fused Damping kernel v2: B=32768, N=64, H=256, OFF=2016.
// One WG = 32 batch rows, 512 threads (8 waves), 1 WG/CU.
// Key change vs v1: the off matrix NEVER materializes. Woo accumulators stay
// in registers; V and OUT contractions scatter directly via ds_add_f32 into
// fp32 LDS arrays. Woo is packed with a column permutation col = ni*128 + nt
// so OUT-scatter addresses are distinct across lanes (k-run length <= 64 < 128).

#define BT 32
#define THREADS 512

typedef short short8 __attribute__((ext_vector_type(8)));
typedef float floatx4 __attribute__((ext_vector_type(4)));

__device__ __forceinline__ ushort f2bf(float f) {
    uint u = __builtin_bit_cast(uint, f);
    u += 0x7FFFu + ((u >> 16) & 1u);   // round-to-nearest-even
    return (ushort)(u >> 16);
}
__device__ __forceinline__ float fast_tanh(float x) {
    // exact at saturation: expf(+inf)->inf => 1-0; expf(-inf)->0 => -1
    return 1.f - 2.f / (__expf(2.f * x) + 1.f);
}
// c -> (k,j) with c = k(k-1)/2 + j, 0 <= j < k   (np.tril_indices(N,-1) order)
__device__ __forceinline__ void tri_decode(int c, int& k, int& j) {
    float f = __fsqrt_rn(8.f * (float)c + 1.f);   // 8c+1 <= 16377 < 2^24: exact arg
    int kk = (int)((1.f + f) * 0.5f);
    int t0 = (kk * (kk - 1)) >> 1;
    if (t0 > c)            { kk--; t0 = (kk * (kk - 1)) >> 1; }
    else if (t0 + kk <= c) { kk++; t0 = (kk * (kk - 1)) >> 1; }
    k = kk; j = c - t0;
}

// ---- unified weight packer (one launch) ----
// Fragment layout: frag idx f = nt*KT + kt; lane holds B[k = kt*32+(lane>>4)*8+j][col],
// col = nt*16 + (lane&15) (standard) or (lane&15)*128 + nt (permuted, Woo only).
// Octet budget: wd1 2048 | wo1 2048 | wd2 8192 | wo2 8192 | wdo 2048 | woo 65536 = 88064
__global__ void pack_all(const float* __restrict__ Wd1, const float* __restrict__ Wd2,
                         const float* __restrict__ Wdo, const float* __restrict__ Wo1,
                         const float* __restrict__ Wo2, const float* __restrict__ Woo,
                         ushort* __restrict__ wd1f, ushort* __restrict__ wd2f,
                         ushort* __restrict__ wdof, ushort* __restrict__ wo1f,
                         ushort* __restrict__ wo2f, ushort* __restrict__ woof) {
    int gid = blockIdx.x * blockDim.x + threadIdx.x;
    const float* W; ushort* dst; int Ncols, KT, perm, lg;
    if (gid < 2048)       { W = Wd1; dst = wd1f; Ncols = 256;  KT = 2; perm = 0; lg = gid; }
    else if (gid < 4096)  { W = Wo1; dst = wo1f; Ncols = 256;  KT = 2; perm = 0; lg = gid - 4096 + 2048; }
    else if (gid < 12288) { W = Wd2; dst = wd2f; Ncols = 256;  KT = 8; perm = 0; lg = gid - 4096; }
    else if (gid < 20480) { W = Wo2; dst = wo2f; Ncols = 256;  KT = 8; perm = 0; lg = gid - 12288; }
    else if (gid < 22528) { W = Wdo; dst = wdof; Ncols = 64;   KT = 8; perm = 0; lg = gid - 20480; }
    else if (gid < 88064) { W = Woo; dst = woof; Ncols = 2016; KT = 8; perm = 1; lg = gid - 22528; }
    else return;
    int lane = lg & 63;
    int kt = (lg >> 6) % KT;
    int nt = lg / (64 * KT);
    int q = lane >> 4, ni = lane & 15;
    int col = perm ? (ni * 128 + nt) : (nt * 16 + ni);
#pragma unroll
    for (int j = 0; j < 8; j++) {
        int k = kt * 32 + q * 8 + j;
        float val = (col < Ncols) ? W[(size_t)k * Ncols + col] : 0.f;
        dst[(size_t)lg * 8 + j] = f2bf(val);
    }
}

// ---- LDS layout (bytes), total 106,880 ----
#define ASTR 264
#define XBF_STR 88
#define XSTR 68
#define VSTR 65
#define ACT_D  0
#define ACT_O  16896
#define ACT_D2 33792
#define ACT_O2 50688
#define XBF_B  67584
#define XS_B   73216
#define DG_B   81920
#define V_B    90240
#define OUT_B  98560
#define LDS_BYTES 106880

#define FRAG(p, idx) (*(const short8*)((p) + (size_t)(idx) * 512 + (size_t)lane * 8))

__global__ __launch_bounds__(THREADS, 2)
void damping_fused(const float* __restrict__ x,
                   const ushort* __restrict__ wd1f, const ushort* __restrict__ wd2f,
                   const ushort* __restrict__ wdof, const ushort* __restrict__ wo1f,
                   const ushort* __restrict__ wo2f, const ushort* __restrict__ woof,
                   const float* __restrict__ bd1, const float* __restrict__ bd2,
                   const float* __restrict__ bdo, const float* __restrict__ bo1,
                   const float* __restrict__ bo2, const float* __restrict__ boo,
                   const float* __restrict__ dmin, float* __restrict__ out) {
    extern __shared__ char smem[];
    ushort* act_d  = (ushort*)(smem + ACT_D);
    ushort* act_o  = (ushort*)(smem + ACT_O);
    ushort* act_d2 = (ushort*)(smem + ACT_D2);
    ushort* act_o2 = (ushort*)(smem + ACT_O2);
    ushort* xbf    = (ushort*)(smem + XBF_B);
    float*  xs     = (float*)(smem + XS_B);
    float*  dg     = (float*)(smem + DG_B);
    float*  v_s    = (float*)(smem + V_B);
    float*  outs   = (float*)(smem + OUT_B);

    const int tid  = threadIdx.x;
    const int lane = tid & 63;
    const int w    = tid >> 6;
    const int q    = lane >> 4;
    const int ni   = lane & 15;
    const int b0   = blockIdx.x * BT;

    // ---- P1: load x tile [32][64] ----
    {
        int row = tid >> 4;
        int c = (tid & 15) * 4;
        const float4 xv = *(const float4*)(x + (size_t)(b0 + row) * 64 + c);
        float* xr = xs + row * XSTR + c;
        xr[0] = xv.x; xr[1] = xv.y; xr[2] = xv.z; xr[3] = xv.w;
        ushort* xb = xbf + row * XBF_STR + c;
        xb[0] = f2bf(xv.x); xb[1] = f2bf(xv.y); xb[2] = f2bf(xv.z); xb[3] = f2bf(xv.w);
    }
    __syncthreads();

    const int br  = w >> 2;          // 0: diag branch, 1: off branch
    const int ntb = (w & 3) * 4;     // 4 N-tiles per wave in 256-col layers

    // ---- P2: layer1 both branches (K=64, KT=2) ----
    {
        const ushort* wf = br ? wo1f : wd1f;
        const float*  bs = br ? bo1 : bd1;
        ushort* aout = br ? act_o : act_d;
        floatx4 acc[4][2] = {};
        for (int kt = 0; kt < 2; kt++) {
            short8 a0 = *(const short8*)(xbf + ni * XBF_STR + kt * 32 + q * 8);
            short8 a1 = *(const short8*)(xbf + (16 + ni) * XBF_STR + kt * 32 + q * 8);
#pragma unroll
            for (int t = 0; t < 4; t++) {
                short8 bf = FRAG(wf, (ntb + t) * 2 + kt);
                acc[t][0] = __builtin_amdgcn_mfma_f32_16x16x32_bf16(a0, bf, acc[t][0], 0, 0, 0);
                acc[t][1] = __builtin_amdgcn_mfma_f32_16x16x32_bf16(a1, bf, acc[t][1], 0, 0, 0);
            }
        }
#pragma unroll
        for (int t = 0; t < 4; t++) {
            int col = (ntb + t) * 16 + ni;
            float bb = bs[col];
#pragma unroll
            for (int m = 0; m < 2; m++)
#pragma unroll
                for (int r = 0; r < 4; r++)
                    aout[(m * 16 + q * 4 + r) * ASTR + col] = f2bf(fast_tanh(acc[t][m][r] + bb));
        }
    }
    __syncthreads();

    // ---- P3: layer2 both branches (K=256, KT=8), separate out buffers ----
    {
        const ushort* wf = br ? wo2f : wd2f;
        const float*  bs = br ? bo2 : bd2;
        const ushort* ain = br ? act_o : act_d;
        ushort* aout = br ? act_o2 : act_d2;
        floatx4 acc[4][2] = {};
        for (int kt = 0; kt < 8; kt++) {
            short8 a0 = *(const short8*)(ain + ni * ASTR + kt * 32 + q * 8);
            short8 a1 = *(const short8*)(ain + (16 + ni) * ASTR + kt * 32 + q * 8);
#pragma unroll
            for (int t = 0; t < 4; t++) {
                short8 bf = FRAG(wf, (ntb + t) * 8 + kt);
                acc[t][0] = __builtin_amdgcn_mfma_f32_16x16x32_bf16(a0, bf, acc[t][0], 0, 0, 0);
                acc[t][1] = __builtin_amdgcn_mfma_f32_16x16x32_bf16(a1, bf, acc[t][1], 0, 0, 0);
            }
        }
#pragma unroll
        for (int t = 0; t < 4; t++) {
            int col = (ntb + t) * 16 + ni;
            float bb = bs[col];
#pragma unroll
            for (int m = 0; m < 2; m++)
#pragma unroll
                for (int r = 0; r < 4; r++)
                    aout[(m * 16 + q * 4 + r) * ASTR + col] = f2bf(fast_tanh(acc[t][m][r] + bb));
        }
    }
    __syncthreads();

    // ---- P4: diag layer3 (all 8 waves: mt = w>>2, nt3 = w&3) + dg + v init ----
    {
        const int mt = w >> 2, nt3 = w & 3;
        floatx4 acc = {};
        for (int kt = 0; kt < 8; kt++) {
            short8 a  = *(const short8*)(act_d2 + (mt * 16 + ni) * ASTR + kt * 32 + q * 8);
            short8 bf = FRAG(wdof, nt3 * 8 + kt);
            acc = __builtin_amdgcn_mfma_f32_16x16x32_bf16(a, bf, acc, 0, 0, 0);
        }
        int col = nt3 * 16 + ni;
        float bb = bdo[col], dm = dmin[col];
#pragma unroll
        for (int r = 0; r < 4; r++) {
            int row = mt * 16 + q * 4 + r;
            float d = acc[r] + bb;
            float diag = ((d > 0.f) ? d : 0.f) + dm;
            float xv = xs[row * XSTR + col];
            diag *= xv;                       // L diagonal entry
            dg[row * VSTR + col]  = diag;
            v_s[row * VSTR + col] = diag * xv; // v init = diag * x
        }
    }
    __syncthreads();

    // ---- P5: Woo GEMM (acc held in regs) + V scatter: v[j] += (off+boo)*x[k] ----
    floatx4 oacc[16][2] = {};
    for (int kt = 0; kt < 8; kt++) {
        short8 a0 = *(const short8*)(act_o2 + ni * ASTR + kt * 32 + q * 8);
        short8 a1 = *(const short8*)(act_o2 + (16 + ni) * ASTR + kt * 32 + q * 8);
#pragma unroll
        for (int t = 0; t < 16; t++) {
            short8 bf = FRAG(woof, (w * 16 + t) * 8 + kt);
            oacc[t][0] = __builtin_amdgcn_mfma_f32_16x16x32_bf16(a0, bf, oacc[t][0], 0, 0, 0);
            oacc[t][1] = __builtin_amdgcn_mfma_f32_16x16x32_bf16(a1, bf, oacc[t][1], 0, 0, 0);
        }
    }
#pragma unroll
    for (int t = 0; t < 16; t++) {
        int c = ni * 128 + w * 16 + t;       // permuted column of this lane's tile-col
        if (c < 2016) {
            int kk, jj; tri_decode(c, kk, jj);
            float bv = boo[c];
#pragma unroll
            for (int m = 0; m < 2; m++)
#pragma unroll
                for (int r = 0; r < 4; r++) {
                    int row = m * 16 + q * 4 + r;
                    float val = oacc[t][m][r] + bv;
                    atomicAdd(&v_s[row * VSTR + jj], val * xs[row * XSTR + kk]);
                }
        }
    }
    __syncthreads();

    // ---- P6a: out init = dg * v ----
    {
        int row = tid >> 4, i0 = (tid & 15) * 4;
#pragma unroll
        for (int e = 0; e < 4; e++) {
            int i = i0 + e;
            outs[row * VSTR + i] = dg[row * VSTR + i] * v_s[row * VSTR + i];
        }
    }
    __syncthreads();

    // ---- P6b: OUT scatter: out[k] += (off+boo)*v[j]  (k distinct per lane) ----
#pragma unroll
    for (int t = 0; t < 16; t++) {
        int c = ni * 128 + w * 16 + t;
        if (c < 2016) {
            int kk, jj; tri_decode(c, kk, jj);
            float bv = boo[c];
#pragma unroll
            for (int m = 0; m < 2; m++)
#pragma unroll
                for (int r = 0; r < 4; r++) {
                    int row = m * 16 + q * 4 + r;
                    float val = oacc[t][m][r] + bv;
                    atomicAdd(&outs[row * VSTR + kk], val * v_s[row * VSTR + jj]);
                }
        }
    }
    __syncthreads();

    // ---- P7: write out ----
    {
        int row = tid >> 4, i0 = (tid & 15) * 4;
        float4 o;
        o.x = outs[row * VSTR + i0];
        o.y = outs[row * VSTR + i0 + 1];
        o.z = outs[row * VSTR + i0 + 2];
        o.w = outs[row * VSTR + i0 + 3];
        *(float4*)(out + (size_t)(b0 + row) * 64 + i0) = o;
    }
}

extern "C" void kernel_launch(void* const* d_in, const int* in_sizes, int n_in,
                              void* d_out, int out_size, void* d_ws, size_t ws_size,
                              hipStream_t stream) {
    const float* x    = (const float*)d_in[0];
    const float* Wd1  = (const float*)d_in[1];
    const float* bd1  = (const float*)d_in[2];
    const float* Wd2  = (const float*)d_in[3];
    const float* bd2  = (const float*)d_in[4];
    const float* Wdo  = (const float*)d_in[5];
    const float* bdo  = (const float*)d_in[6];
    const float* Wo1  = (const float*)d_in[7];
    const float* bo1  = (const float*)d_in[8];
    const float* Wo2  = (const float*)d_in[9];
    const float* bo2  = (const float*)d_in[10];
    const float* Woo  = (const float*)d_in[11];
    const float* boo  = (const float*)d_in[12];
    const float* dmin = (const float*)d_in[13];
    float* out = (float*)d_out;

    // ws layout (ushort elems): wd1f 16384 | wd2f 65536 | wdof 16384 | wo1f 16384
    //                           | wo2f 65536 | woof 524288  => 1,409,024 bytes
    ushort* ws   = (ushort*)d_ws;
    ushort* wd1f = ws;
    ushort* wd2f = wd1f + 16384;
    ushort* wdof = wd2f + 65536;
    ushort* wo1f = wdof + 16384;
    ushort* wo2f = wo1f + 16384;
    ushort* woof = wo2f + 65536;

    pack_all<<<344, 256, 0, stream>>>(Wd1, Wd2, Wdo, Wo1, Wo2, Woo,
                                      wd1f, wd2f, wdof, wo1f, wo2f, woof);

    hipFuncSetAttribute((const void*)damping_fused,
                        hipFuncAttributeMaxDynamicSharedMemorySize, LDS_BYTES);

    damping_fused<<<32768 / BT, THREADS, LDS_BYTES, stream>>>(
        x, wd1f, wd2f, wdof, wo1f, wo2f, woof,
        bd1, bd2, bdo, bo1, bo2, boo, dmin, out);
}

// Round 3
// 250.916 us; speedup vs baseline: 3.4769x; 3.4769x over previous
//
#include <hip/hip_runtime.h>

// Fused Damping v3: B=32768, N=64, H=256, OFF=2016.
// BT=16 rows/WG, 512 threads (8 waves), LDS 77,952 B -> 2 WGs/CU.
// off stored bf16 in LDS in padded-triangle "p-space": row k starts at
// s(k) = (k*k - (k&1))/2 (always even), odd rows get one pad slot ->
// all V/OUT reads are aligned u32 pairs. Woo is packed directly in p-space
// (pad cols = zero weight/bias), so the kernel never decodes p->(k,j).

#define BT 16
#define THREADS 512
#define OSTR 2052            // ushorts per batch-row (2048 used); 4*1026%32==8 -> epilogue writes conflict-free

typedef short short8 __attribute__((ext_vector_type(8)));
typedef float floatx4 __attribute__((ext_vector_type(4)));

__device__ __forceinline__ ushort f2bf(float f) {
    uint u = __builtin_bit_cast(uint, f);
    u += 0x7FFFu + ((u >> 16) & 1u);
    return (ushort)(u >> 16);
}
__device__ __forceinline__ float bf2f(ushort h) {
    return __builtin_bit_cast(float, ((uint)h) << 16);
}
__device__ __forceinline__ float fast_tanh(float x) {
    return 1.f - 2.f / (__expf(2.f * x) + 1.f);
}

// ---- unified weight packer ----
// Standard frags: lane holds B[k=kt*32+(lane>>4)*8+j][col], col = nt*16+(lane&15).
// Woo frags: col is a PADDED p-space index (0..2047); p -> (k,j) decoded here;
// j>=k is a pad slot (zero weight). Also fills boo_p[2048] (bias in p-space).
// Octets: wd1 2048 | wo1 2048 | wd2 8192 | wo2 8192 | wdo 2048 | woo 65536 = 88064
// gids [88064, 90112) fill boo_p.
__global__ void pack_all(const float* __restrict__ Wd1, const float* __restrict__ Wd2,
                         const float* __restrict__ Wdo, const float* __restrict__ Wo1,
                         const float* __restrict__ Wo2, const float* __restrict__ Woo,
                         const float* __restrict__ boo,
                         ushort* __restrict__ wd1f, ushort* __restrict__ wd2f,
                         ushort* __restrict__ wdof, ushort* __restrict__ wo1f,
                         ushort* __restrict__ wo2f, ushort* __restrict__ woof,
                         float* __restrict__ boo_p) {
    int gid = blockIdx.x * blockDim.x + threadIdx.x;
    if (gid >= 88064) {
        int p = gid - 88064;
        if (p < 2048) {
            int k = (int)sqrtf(2.f * p + 1.f);
            while ((k + 1) * (k + 1) - ((k + 1) & 1) <= 2 * p) k++;
            while (k * k - (k & 1) > 2 * p) k--;
            int j = p - ((k * k - (k & 1)) >> 1);
            boo_p[p] = (j < k) ? boo[k * (k - 1) / 2 + j] : 0.f;
        }
        return;
    }
    const float* W; ushort* dst; int Ncols, KT, woo, lg;
    if (gid < 2048)       { W = Wd1; dst = wd1f; Ncols = 256; KT = 2; woo = 0; lg = gid; }
    else if (gid < 4096)  { W = Wo1; dst = wo1f; Ncols = 256; KT = 2; woo = 0; lg = gid - 2048; }
    else if (gid < 12288) { W = Wd2; dst = wd2f; Ncols = 256; KT = 8; woo = 0; lg = gid - 4096; }
    else if (gid < 20480) { W = Wo2; dst = wo2f; Ncols = 256; KT = 8; woo = 0; lg = gid - 12288; }
    else if (gid < 22528) { W = Wdo; dst = wdof; Ncols = 64;  KT = 8; woo = 0; lg = gid - 20480; }
    else                  { W = Woo; dst = woof; Ncols = 2016; KT = 8; woo = 1; lg = gid - 22528; }
    int lane = lg & 63;
    int kt = (lg >> 6) % KT;
    int nt = lg / (64 * KT);
    int q = lane >> 4, ni = lane & 15;
    int col = nt * 16 + ni;       // for Woo this is the padded p-index
    int valid = 1;
    if (woo) {
        int p = col;
        int k = (int)sqrtf(2.f * p + 1.f);
        while ((k + 1) * (k + 1) - ((k + 1) & 1) <= 2 * p) k++;
        while (k * k - (k & 1) > 2 * p) k--;
        int j = p - ((k * k - (k & 1)) >> 1);
        valid = (j < k);
        col = valid ? (k * (k - 1) / 2 + j) : 0;
    }
#pragma unroll
    for (int j = 0; j < 8; j++) {
        int k = kt * 32 + q * 8 + j;
        float val = (valid && col < Ncols) ? W[(size_t)k * Ncols + col] : 0.f;
        dst[(size_t)lg * 8 + j] = f2bf(val);
    }
}

// ---- LDS layout (bytes), total 77,952 -> 2 WGs/CU ----
// off:  [16][2052] ushort @ 0         (65,664)
//   overlays inside off region (dead before off is written, barrier-protected):
//   xbf  @ 0      [16][88]  ushort (2,816)   P1w / P2r
//   act_d @ 4096  [16][264] ushort (8,448)   P2w / P3r
//   act_o @ 12544 [16][264] ushort (8,448)   P2w / P3r
//   act_d2@ 20992 [16][264] ushort (8,448)   P3w / P4r
//   act_o2@ 29440 [16][264] ushort (8,448)   P3w / P5r   (ends 37,888)
// xs:  [16][64] f32 @ 65664  (4,096)
// dg:  [16][64] f32 @ 69760  (4,096)
// v_s: [16][64] f32 @ 73856  (4,096)
#define ASTR 264
#define XBF_STR 88
#define ACT_D  4096
#define ACT_O  12544
#define ACT_D2 20992
#define ACT_O2 29440
#define XS_B   65664
#define DG_B   69760
#define V_B    73856
#define LDS_BYTES 77952

#define FRAG(p, idx) (*(const short8*)((p) + (size_t)(idx) * 512 + (size_t)lane * 8))

__global__ __launch_bounds__(THREADS, 4)
void damping_fused(const float* __restrict__ x,
                   const ushort* __restrict__ wd1f, const ushort* __restrict__ wd2f,
                   const ushort* __restrict__ wdof, const ushort* __restrict__ wo1f,
                   const ushort* __restrict__ wo2f, const ushort* __restrict__ woof,
                   const float* __restrict__ bd1, const float* __restrict__ bd2,
                   const float* __restrict__ bdo, const float* __restrict__ bo1,
                   const float* __restrict__ bo2, const float* __restrict__ boo_p,
                   const float* __restrict__ dmin, float* __restrict__ out) {
    extern __shared__ char smem[];
    ushort* off_s  = (ushort*)smem;
    ushort* xbf    = (ushort*)smem;
    ushort* act_d  = (ushort*)(smem + ACT_D);
    ushort* act_o  = (ushort*)(smem + ACT_O);
    ushort* act_d2 = (ushort*)(smem + ACT_D2);
    ushort* act_o2 = (ushort*)(smem + ACT_O2);
    float*  xs     = (float*)(smem + XS_B);
    float*  dg     = (float*)(smem + DG_B);
    float*  v_s    = (float*)(smem + V_B);

    const int tid  = threadIdx.x;
    const int lane = tid & 63;
    const int w    = tid >> 6;
    const int q    = lane >> 4;
    const int ni   = lane & 15;
    const int b0   = blockIdx.x * BT;

    // ---- P1: load x tile [16][64] ----
    if (tid < 256) {
        int row = tid >> 4;
        int c = (tid & 15) * 4;
        const float4 xv = *(const float4*)(x + (size_t)(b0 + row) * 64 + c);
        float* xr = xs + row * 64 + c;
        xr[0] = xv.x; xr[1] = xv.y; xr[2] = xv.z; xr[3] = xv.w;
        ushort* xb = xbf + row * XBF_STR + c;
        xb[0] = f2bf(xv.x); xb[1] = f2bf(xv.y); xb[2] = f2bf(xv.z); xb[3] = f2bf(xv.w);
    }
    __syncthreads();

    const int br  = w >> 2;          // 0: diag branch, 1: off branch
    const int ntb = (w & 3) * 4;     // 4 N-tiles per wave per branch

    // ---- P2: layer1 (K=64) ----
    {
        const ushort* wf = br ? wo1f : wd1f;
        const float*  bs = br ? bo1 : bd1;
        ushort* aout = br ? act_o : act_d;
        floatx4 acc[4] = {};
        for (int kt = 0; kt < 2; kt++) {
            short8 a = *(const short8*)(xbf + ni * XBF_STR + kt * 32 + q * 8);
#pragma unroll
            for (int t = 0; t < 4; t++) {
                short8 bf = FRAG(wf, (ntb + t) * 2 + kt);
                acc[t] = __builtin_amdgcn_mfma_f32_16x16x32_bf16(a, bf, acc[t], 0, 0, 0);
            }
        }
#pragma unroll
        for (int t = 0; t < 4; t++) {
            int col = (ntb + t) * 16 + ni;
            float bb = bs[col];
#pragma unroll
            for (int r = 0; r < 4; r++)
                aout[(q * 4 + r) * ASTR + col] = f2bf(fast_tanh(acc[t][r] + bb));
        }
    }
    __syncthreads();

    // ---- P3: layer2 (K=256) ----
    {
        const ushort* wf = br ? wo2f : wd2f;
        const float*  bs = br ? bo2 : bd2;
        const ushort* ain = br ? act_o : act_d;
        ushort* aout = br ? act_o2 : act_d2;
        floatx4 acc[4] = {};
        for (int kt = 0; kt < 8; kt++) {
            short8 a = *(const short8*)(ain + ni * ASTR + kt * 32 + q * 8);
#pragma unroll
            for (int t = 0; t < 4; t++) {
                short8 bf = FRAG(wf, (ntb + t) * 8 + kt);
                acc[t] = __builtin_amdgcn_mfma_f32_16x16x32_bf16(a, bf, acc[t], 0, 0, 0);
            }
        }
#pragma unroll
        for (int t = 0; t < 4; t++) {
            int col = (ntb + t) * 16 + ni;
            float bb = bs[col];
#pragma unroll
            for (int r = 0; r < 4; r++)
                aout[(q * 4 + r) * ASTR + col] = f2bf(fast_tanh(acc[t][r] + bb));
        }
    }
    __syncthreads();

    // ---- P4 (waves 0-3): diag layer3 [16][64] -> dg = (relu+dmin)*x ----
    if (w < 4) {
        floatx4 acc = {};
        for (int kt = 0; kt < 8; kt++) {
            short8 a  = *(const short8*)(act_d2 + ni * ASTR + kt * 32 + q * 8);
            short8 bf = FRAG(wdof, w * 8 + kt);
            acc = __builtin_amdgcn_mfma_f32_16x16x32_bf16(a, bf, acc, 0, 0, 0);
        }
        int col = w * 16 + ni;
        float bb = bdo[col], dm = dmin[col];
#pragma unroll
        for (int r = 0; r < 4; r++) {
            int row = q * 4 + r;
            float d = acc[r] + bb;
            dg[row * 64 + col] = (((d > 0.f) ? d : 0.f) + dm) * xs[row * 64 + col];
        }
    }

    // ---- P5: Woo GEMM [16][2048-padded], acc in regs (64 VGPRs) ----
    floatx4 oacc[16] = {};
    for (int kt = 0; kt < 8; kt++) {
        short8 a = *(const short8*)(act_o2 + ni * ASTR + kt * 32 + q * 8);
#pragma unroll
        for (int t = 0; t < 16; t++) {
            short8 bf = FRAG(woof, (w * 16 + t) * 8 + kt);
            oacc[t] = __builtin_amdgcn_mfma_f32_16x16x32_bf16(a, bf, oacc[t], 0, 0, 0);
        }
    }
    __syncthreads();   // act_d2/act_o2 reads done -> safe to overwrite off region

    // ---- P5e: write off in p-space ----
#pragma unroll
    for (int t = 0; t < 16; t++) {
        int p = (w * 16 + t) * 16 + ni;
        float bv = boo_p[p];
#pragma unroll
        for (int r = 0; r < 4; r++)
            off_s[(q * 4 + r) * OSTR + p] = f2bf(oacc[t][r] + bv);
    }
    __syncthreads();

    // ---- V: v[j] = dg[j]*x[j] + sum_{k>j} off[s(k)+j]*x[k] ----
    // lane-halves process triangle rows k and k+1 simultaneously; each lane
    // reads an aligned u32 (2 bf16) covering j = 2*jl, 2*jl+1.
    const int h = lane >> 5, jl = lane & 31;
    for (int rr = 0; rr < 2; rr++) {
        int b = w * 2 + rr;
        float s0 = 0.f, s1 = 0.f;
        for (int i = 0; i < 32; i++) {
            int k = 2 * i + 1 + h;
            if (k < 64) {
                int sk = (k * k - (k & 1)) >> 1;
                uint u = *(const uint*)(off_s + b * OSTR + sk + 2 * jl);
                float xk = xs[b * 64 + k];
                float lo = bf2f((ushort)u), hi = bf2f((ushort)(u >> 16));
                s0 += (2 * jl     < k) ? lo * xk : 0.f;
                s1 += (2 * jl + 1 < k) ? hi * xk : 0.f;
            }
        }
        s0 += __shfl_xor(s0, 32);
        s1 += __shfl_xor(s1, 32);
        if (h == 0) {
            int j0 = 2 * jl;
            float2 vv;
            vv.x = s0 + dg[b * 64 + j0] * xs[b * 64 + j0];
            vv.y = s1 + dg[b * 64 + j0 + 1] * xs[b * 64 + j0 + 1];
            *(float2*)(v_s + b * 64 + j0) = vv;
        }
    }
    __syncthreads();

    // ---- OUT: out[i] = dg[i]*v[i] + sum_{j<i} off[s(i)+j]*v[j] ----
    for (int rr = 0; rr < 2; rr++) {
        int b = w * 2 + rr;
        int i = lane;
        int si = (i * i - (i & 1)) >> 1;
        float o = dg[b * 64 + i] * v_s[b * 64 + i];
        for (int j = 0; j < 63; j += 2) {
            uint u = *(const uint*)(off_s + b * OSTR + si + j);
            float2 vj = *(const float2*)(v_s + b * 64 + j);
            float lo = bf2f((ushort)u), hi = bf2f((ushort)(u >> 16));
            o += (j     < i) ? lo * vj.x : 0.f;
            o += (j + 1 < i) ? hi * vj.y : 0.f;
        }
        out[(size_t)(b0 + b) * 64 + i] = o;
    }
}

extern "C" void kernel_launch(void* const* d_in, const int* in_sizes, int n_in,
                              void* d_out, int out_size, void* d_ws, size_t ws_size,
                              hipStream_t stream) {
    const float* x    = (const float*)d_in[0];
    const float* Wd1  = (const float*)d_in[1];
    const float* bd1  = (const float*)d_in[2];
    const float* Wd2  = (const float*)d_in[3];
    const float* bd2  = (const float*)d_in[4];
    const float* Wdo  = (const float*)d_in[5];
    const float* bdo  = (const float*)d_in[6];
    const float* Wo1  = (const float*)d_in[7];
    const float* bo1  = (const float*)d_in[8];
    const float* Wo2  = (const float*)d_in[9];
    const float* bo2  = (const float*)d_in[10];
    const float* Woo  = (const float*)d_in[11];
    const float* boo  = (const float*)d_in[12];
    const float* dmin = (const float*)d_in[13];
    float* out = (float*)d_out;

    // ws (ushort elems): wd1f 16384 | wd2f 65536 | wdof 16384 | wo1f 16384
    //                    | wo2f 65536 | woof 524288 | boo_p (2048 f32)
    ushort* ws   = (ushort*)d_ws;
    ushort* wd1f = ws;
    ushort* wd2f = wd1f + 16384;
    ushort* wdof = wd2f + 65536;
    ushort* wo1f = wdof + 16384;
    ushort* wo2f = wo1f + 16384;
    ushort* woof = wo2f + 65536;
    float*  boo_p = (float*)(woof + 524288);

    pack_all<<<352, 256, 0, stream>>>(Wd1, Wd2, Wdo, Wo1, Wo2, Woo, boo,
                                      wd1f, wd2f, wdof, wo1f, wo2f, woof, boo_p);

    hipFuncSetAttribute((const void*)damping_fused,
                        hipFuncAttributeMaxDynamicSharedMemorySize, LDS_BYTES);

    damping_fused<<<32768 / BT, THREADS, LDS_BYTES, stream>>>(
        x, wd1f, wd2f, wdof, wo1f, wo2f, woof,
        bd1, bd2, bdo, bo1, bo2, boo_p, dmin, out);
}

// Round 4
// 243.310 us; speedup vs baseline: 3.5856x; 1.0313x over previous
//
#include <hip/hip_runtime.h>

// Fused Damping v4: B=32768, N=64, H=256, OFF=2016.
// BT=16 rows/WG, 512 threads, LDS 80,640 B -> 2 WGs/CU.
// All GEMMs use SWAPPED operands: A=weight frags (global), B=activation frags
// (LDS, lane&15 = batch row). D: row(q*4+r)=output col, col(lane&15)=batch ->
// epilogues write 4 consecutive cols as packed bf16 (b64 writes).
// off lives in LDS in 8-padded 16B-aligned triangle rows (zero pads from the
// packer) -> V/OUT phases are ds_read_b128 chunk loops, conflict-free.

#define BT 16
#define THREADS 512

typedef short short8 __attribute__((ext_vector_type(8)));
typedef float floatx4 __attribute__((ext_vector_type(4)));

__device__ __forceinline__ ushort f2bf(float f) {
    uint u = __builtin_bit_cast(uint, f);
    u += 0x7FFFu + ((u >> 16) & 1u);
    return (ushort)(u >> 16);
}
__device__ __forceinline__ uint pk2bf(float lo, float hi) {
    uint a = __builtin_bit_cast(uint, lo);
    a += 0x7FFFu + ((a >> 16) & 1u);
    uint b = __builtin_bit_cast(uint, hi);
    b += 0x7FFFu + ((b >> 16) & 1u);
    return (a >> 16) | (b & 0xFFFF0000u);
}
__device__ __forceinline__ float bf2f(ushort h) {
    return __builtin_bit_cast(float, ((uint)h) << 16);
}
__device__ __forceinline__ float bflo(uint u) { return __builtin_bit_cast(float, u << 16); }
__device__ __forceinline__ float bfhi(uint u) { return __builtin_bit_cast(float, u & 0xFFFF0000u); }
__device__ __forceinline__ float fast_tanh(float x) {
    return 1.f - 2.f / (__expf(2.f * x) + 1.f);
}
// start (in ushorts) of 8-padded triangle row k: 8 * sum_{m<k} ceil(m/8)
__device__ __forceinline__ int s8idx(int k) {
    int a = k >> 3, r = k & 7;
    return 8 * (r ? (a + 1) * (4 * a + r - 1) : a * (4 * a + 3));
}

// ---- pack: one thread per fragment element (coalesced u16 writes) ----
// Octet ranges: wd1[0,2048) wo1[2048,4096) wd2[4096,12288) wo2[12288,20480)
// wdo[20480,22528) woo[22528,94208). Element threads = 94208*8 = 753664.
// gids [753664, 753664+2240): boo in p8-space (pads = 0).
__global__ void pack_all(const float* __restrict__ Wd1, const float* __restrict__ Wd2,
                         const float* __restrict__ Wdo, const float* __restrict__ Wo1,
                         const float* __restrict__ Wo2, const float* __restrict__ Woo,
                         const float* __restrict__ boo,
                         ushort* __restrict__ ws, float* __restrict__ boo_p8) {
    int gid = blockIdx.x * blockDim.x + threadIdx.x;
    if (gid >= 753664) {
        int p = gid - 753664;
        if (p < 2240) {
            int kr = (int)sqrtf(2.f * (float)p);
            if (kr < 1) kr = 1;
            if (kr > 63) kr = 63;
            while (kr < 63 && s8idx(kr + 1) <= p) kr++;
            while (kr > 1 && s8idx(kr) > p) kr--;
            int jj = p - s8idx(kr);
            boo_p8[p] = (jj < kr) ? boo[kr * (kr - 1) / 2 + jj] : 0.f;
        }
        return;
    }
    int oct = gid >> 3, j = gid & 7;
    const float* W; int base, Ncols, KT, woo;
    if (oct < 2048)       { W = Wd1; base = 0;     Ncols = 256;  KT = 2; woo = 0; }
    else if (oct < 4096)  { W = Wo1; base = 2048;  Ncols = 256;  KT = 2; woo = 0; }
    else if (oct < 12288) { W = Wd2; base = 4096;  Ncols = 256;  KT = 8; woo = 0; }
    else if (oct < 20480) { W = Wo2; base = 12288; Ncols = 256;  KT = 8; woo = 0; }
    else if (oct < 22528) { W = Wdo; base = 20480; Ncols = 64;   KT = 8; woo = 0; }
    else                  { W = Woo; base = 22528; Ncols = 2016; KT = 8; woo = 1; }
    int lg = oct - base;
    int lane = lg & 63;
    int kt = (lg >> 6) % KT;
    int tile = lg / (64 * KT);
    int q = lane >> 4, ni = lane & 15;
    int col = tile * 16 + ni;            // A-operand outer index (out-col / p8 idx)
    int valid = 1;
    if (woo) {
        int p = col;
        int kr = (int)sqrtf(2.f * (float)p);
        if (kr < 1) kr = 1;
        if (kr > 63) kr = 63;
        while (kr < 63 && s8idx(kr + 1) <= p) kr++;
        while (kr > 1 && s8idx(kr) > p) kr--;
        int jj = p - s8idx(kr);
        valid = (jj < kr);
        col = valid ? (kr * (kr - 1) / 2 + jj) : 0;
    }
    int k = kt * 32 + q * 8 + j;
    float val = valid ? W[(size_t)k * Ncols + col] : 0.f;
    ws[(size_t)oct * 8 + j] = f2bf(val);
}

// ---- LDS layout (bytes), total 80,640 -> 2 WGs/CU ----
// off8: [16][2248] ushort @ 0  (71,936)  batch stride 1124 dw (== 4 mod 32)
//   overlays (dead before off8 written): xbf @0 [16][88]us;
//   act_d@4096 act_o@12544 act_d2@20992 act_o2@29440 (each [16][264]us, 8448B)
// xs  [16][64] f32  @ 71936 (4096)
// dgb [16][72] bf16 @ 76032 (2304)
// vb  [16][72] bf16 @ 78336 (2304)
#define BSTR8 2248
#define XBF_STR 88
#define ASTR 264
#define DGSTR 72
#define ACT_D  4096
#define ACT_O  12544
#define ACT_D2 20992
#define ACT_O2 29440
#define XS_B   71936
#define DG_B   76032
#define VB_B   78336
#define LDS_BYTES 80640

#define FRAGW(p, idx) (*(const short8*)((p) + (size_t)(idx) * 512 + (size_t)lane * 8))

__global__ __launch_bounds__(THREADS, 4)
void damping_fused(const float* __restrict__ x,
                   const ushort* __restrict__ wd1f, const ushort* __restrict__ wd2f,
                   const ushort* __restrict__ wdof, const ushort* __restrict__ wo1f,
                   const ushort* __restrict__ wo2f, const ushort* __restrict__ woof,
                   const float* __restrict__ bd1, const float* __restrict__ bd2,
                   const float* __restrict__ bdo, const float* __restrict__ bo1,
                   const float* __restrict__ bo2, const float* __restrict__ boo_p8,
                   const float* __restrict__ dmin, float* __restrict__ out) {
    extern __shared__ char smem[];
    ushort* off8   = (ushort*)smem;
    ushort* xbf    = (ushort*)smem;
    ushort* act_d  = (ushort*)(smem + ACT_D);
    ushort* act_o  = (ushort*)(smem + ACT_O);
    ushort* act_d2 = (ushort*)(smem + ACT_D2);
    ushort* act_o2 = (ushort*)(smem + ACT_O2);
    float*  xs     = (float*)(smem + XS_B);
    ushort* dgb    = (ushort*)(smem + DG_B);
    ushort* vb     = (ushort*)(smem + VB_B);

    const int tid  = threadIdx.x;
    const int lane = tid & 63;
    const int w    = tid >> 6;
    const int q    = lane >> 4;
    const int ni   = lane & 15;
    const int b0   = blockIdx.x * BT;

    // ---- P1: load x [16][64] fp32 + bf16 mirror ----
    if (tid < 256) {
        int row = tid >> 4;
        int c = (tid & 15) * 4;
        const float4 xv = *(const float4*)(x + (size_t)(b0 + row) * 64 + c);
        float* xr = xs + row * 64 + c;
        xr[0] = xv.x; xr[1] = xv.y; xr[2] = xv.z; xr[3] = xv.w;
        uint2 p;
        p.x = pk2bf(xv.x, xv.y);
        p.y = pk2bf(xv.z, xv.w);
        *(uint2*)(xbf + row * XBF_STR + c) = p;
    }
    __syncthreads();

    const int br = w >> 2;           // 0: diag branch, 1: off branch

    // ---- P2: layer1 (K=64) ----
    {
        const ushort* wf = br ? wo1f : wd1f;
        const float*  bs = br ? bo1 : bd1;
        ushort* aout = br ? act_o : act_d;
        floatx4 acc[4] = {};
        for (int kt = 0; kt < 2; kt++) {
            short8 bfrg = *(const short8*)(xbf + ni * XBF_STR + kt * 32 + q * 8);
#pragma unroll
            for (int tt = 0; tt < 4; tt++) {
                short8 af = FRAGW(wf, ((w & 3) * 4 + tt) * 2 + kt);
                acc[tt] = __builtin_amdgcn_mfma_f32_16x16x32_bf16(af, bfrg, acc[tt], 0, 0, 0);
            }
        }
#pragma unroll
        for (int tt = 0; tt < 4; tt++) {
            int col0 = ((w & 3) * 4 + tt) * 16 + q * 4;
            float4 bias = *(const float4*)(bs + col0);
            uint2 p;
            p.x = pk2bf(fast_tanh(acc[tt][0] + bias.x), fast_tanh(acc[tt][1] + bias.y));
            p.y = pk2bf(fast_tanh(acc[tt][2] + bias.z), fast_tanh(acc[tt][3] + bias.w));
            *(uint2*)(aout + ni * ASTR + col0) = p;
        }
    }
    __syncthreads();

    // ---- P3: layer2 (K=256) ----
    {
        const ushort* wf = br ? wo2f : wd2f;
        const float*  bs = br ? bo2 : bd2;
        const ushort* ain = br ? act_o : act_d;
        ushort* aout = br ? act_o2 : act_d2;
        floatx4 acc[4] = {};
        for (int kt = 0; kt < 8; kt++) {
            short8 bfrg = *(const short8*)(ain + ni * ASTR + kt * 32 + q * 8);
#pragma unroll
            for (int tt = 0; tt < 4; tt++) {
                short8 af = FRAGW(wf, ((w & 3) * 4 + tt) * 8 + kt);
                acc[tt] = __builtin_amdgcn_mfma_f32_16x16x32_bf16(af, bfrg, acc[tt], 0, 0, 0);
            }
        }
#pragma unroll
        for (int tt = 0; tt < 4; tt++) {
            int col0 = ((w & 3) * 4 + tt) * 16 + q * 4;
            float4 bias = *(const float4*)(bs + col0);
            uint2 p;
            p.x = pk2bf(fast_tanh(acc[tt][0] + bias.x), fast_tanh(acc[tt][1] + bias.y));
            p.y = pk2bf(fast_tanh(acc[tt][2] + bias.z), fast_tanh(acc[tt][3] + bias.w));
            *(uint2*)(aout + ni * ASTR + col0) = p;
        }
    }
    __syncthreads();

    // ---- P4 (waves 0-3): diag layer3 -> dg = (relu(d)+dmin)*x  (bf16) ----
    if (w < 4) {
        floatx4 acc = {};
        for (int kt = 0; kt < 8; kt++) {
            short8 bfrg = *(const short8*)(act_d2 + ni * ASTR + kt * 32 + q * 8);
            short8 af = FRAGW(wdof, w * 8 + kt);
            acc = __builtin_amdgcn_mfma_f32_16x16x32_bf16(af, bfrg, acc, 0, 0, 0);
        }
        int col0 = w * 16 + q * 4;
        float4 bias = *(const float4*)(bdo + col0);
        float4 dmv  = *(const float4*)(dmin + col0);
        float g0, g1, g2, g3;
        {
            float d;
            d = acc[0] + bias.x; g0 = ((d > 0.f) ? d : 0.f) + dmv.x;
            d = acc[1] + bias.y; g1 = ((d > 0.f) ? d : 0.f) + dmv.y;
            d = acc[2] + bias.z; g2 = ((d > 0.f) ? d : 0.f) + dmv.z;
            d = acc[3] + bias.w; g3 = ((d > 0.f) ? d : 0.f) + dmv.w;
        }
        g0 *= xs[ni * 64 + col0];
        g1 *= xs[ni * 64 + col0 + 1];
        g2 *= xs[ni * 64 + col0 + 2];
        g3 *= xs[ni * 64 + col0 + 3];
        uint2 p;
        p.x = pk2bf(g0, g1);
        p.y = pk2bf(g2, g3);
        *(uint2*)(dgb + ni * DGSTR + col0) = p;
    }

    // ---- P5: Woo GEMM (140 p8-tiles, tile = t*8+w) ----
    floatx4 oacc[17];
#pragma unroll
    for (int t = 0; t < 17; t++) oacc[t] = (floatx4){0.f, 0.f, 0.f, 0.f};
    floatx4 oaccx = {};
    for (int kt = 0; kt < 8; kt++) {
        short8 bfrg = *(const short8*)(act_o2 + ni * ASTR + kt * 32 + q * 8);
#pragma unroll
        for (int t = 0; t < 17; t++) {
            short8 af = FRAGW(woof, (size_t)(t * 8 + w) * 8 + kt);
            oacc[t] = __builtin_amdgcn_mfma_f32_16x16x32_bf16(af, bfrg, oacc[t], 0, 0, 0);
        }
        if (w < 4) {
            short8 af = FRAGW(woof, (size_t)(136 + w) * 8 + kt);
            oaccx = __builtin_amdgcn_mfma_f32_16x16x32_bf16(af, bfrg, oaccx, 0, 0, 0);
        }
    }
    __syncthreads();   // all act reads done -> off8 region reusable

    // ---- P5e: write off8 (+bias), packed b64 per tile ----
#pragma unroll
    for (int t = 0; t < 17; t++) {
        int p0 = (t * 8 + w) * 16 + q * 4;
        float4 bias = *(const float4*)(boo_p8 + p0);
        uint2 pw;
        pw.x = pk2bf(oacc[t][0] + bias.x, oacc[t][1] + bias.y);
        pw.y = pk2bf(oacc[t][2] + bias.z, oacc[t][3] + bias.w);
        *(uint2*)(off8 + ni * BSTR8 + p0) = pw;
    }
    if (w < 4) {
        int p0 = (136 + w) * 16 + q * 4;
        float4 bias = *(const float4*)(boo_p8 + p0);
        uint2 pw;
        pw.x = pk2bf(oaccx[0] + bias.x, oaccx[1] + bias.y);
        pw.y = pk2bf(oaccx[2] + bias.z, oaccx[3] + bias.w);
        *(uint2*)(off8 + ni * BSTR8 + p0) = pw;
    }
    __syncthreads();

    // ---- V: v[j] = dg[j]*x[j] + sum_{k>j} off[k][j]*x[k]  (chunked b128) ----
    const int ko = lane >> 3, jb = lane & 7;
    for (int rr = 0; rr < 2; rr++) {
        int b = w * 2 + rr;
        const ushort* rowb = off8 + b * BSTR8;
        float s[8] = {0.f, 0.f, 0.f, 0.f, 0.f, 0.f, 0.f, 0.f};
#pragma unroll
        for (int kk = 0; kk < 8; kk++) {
            int k = kk * 8 + ko;
            uint4 u = *(const uint4*)(rowb + s8idx(k) + 8 * jb);
            float xk = xs[b * 64 + k];
            xk = (8 * jb < k) ? xk : 0.f;
            s[0] += bflo(u.x) * xk; s[1] += bfhi(u.x) * xk;
            s[2] += bflo(u.y) * xk; s[3] += bfhi(u.y) * xk;
            s[4] += bflo(u.z) * xk; s[5] += bfhi(u.z) * xk;
            s[6] += bflo(u.w) * xk; s[7] += bfhi(u.w) * xk;
        }
#pragma unroll
        for (int e = 0; e < 8; e++) {
            s[e] += __shfl_xor(s[e], 8);
            s[e] += __shfl_xor(s[e], 16);
            s[e] += __shfl_xor(s[e], 32);
        }
        if (lane < 8) {               // ko==0, jb==lane
            int j0 = lane * 8;
            uint4 d = *(const uint4*)(dgb + b * DGSTR + j0);
            float4 xa = *(const float4*)(xs + b * 64 + j0);
            float4 xc = *(const float4*)(xs + b * 64 + j0 + 4);
            s[0] += bflo(d.x) * xa.x; s[1] += bfhi(d.x) * xa.y;
            s[2] += bflo(d.y) * xa.z; s[3] += bfhi(d.y) * xa.w;
            s[4] += bflo(d.z) * xc.x; s[5] += bfhi(d.z) * xc.y;
            s[6] += bflo(d.w) * xc.z; s[7] += bfhi(d.w) * xc.w;
            uint4 o;
            o.x = pk2bf(s[0], s[1]); o.y = pk2bf(s[2], s[3]);
            o.z = pk2bf(s[4], s[5]); o.w = pk2bf(s[6], s[7]);
            *(uint4*)(vb + b * DGSTR + j0) = o;
        }
    }
    __syncthreads();

    // ---- OUT: out[i] = dg[i]*v[i] + sum_{j<i} off[i][j]*v[j] ----
    const int io = lane >> 3;
    for (int rr = 0; rr < 2; rr++) {
        int b = w * 2 + rr;
        const ushort* rowb = off8 + b * BSTR8;
        uint4 vv = *(const uint4*)(vb + b * DGSTR + 8 * jb);
        float v0 = bflo(vv.x), v1 = bfhi(vv.x), v2 = bflo(vv.y), v3 = bfhi(vv.y);
        float v4 = bflo(vv.z), v5 = bfhi(vv.z), v6 = bflo(vv.w), v7 = bfhi(vv.w);
#pragma unroll
        for (int ig = 0; ig < 8; ig++) {
            int i = ig * 8 + io;
            uint4 u = *(const uint4*)(rowb + s8idx(i) + 8 * jb);
            float t;
            t  = bflo(u.x) * v0; t += bfhi(u.x) * v1;
            t += bflo(u.y) * v2; t += bfhi(u.y) * v3;
            t += bflo(u.z) * v4; t += bfhi(u.z) * v5;
            t += bflo(u.w) * v6; t += bfhi(u.w) * v7;
            t = (8 * jb < i) ? t : 0.f;
            t += __shfl_xor(t, 1);
            t += __shfl_xor(t, 2);
            t += __shfl_xor(t, 4);
            if (jb == 0) {
                float dgi = bf2f(dgb[b * DGSTR + i]);
                float vi  = bf2f(vb[b * DGSTR + i]);
                out[(size_t)(b0 + b) * 64 + i] = t + dgi * vi;
            }
        }
    }
}

extern "C" void kernel_launch(void* const* d_in, const int* in_sizes, int n_in,
                              void* d_out, int out_size, void* d_ws, size_t ws_size,
                              hipStream_t stream) {
    const float* x    = (const float*)d_in[0];
    const float* Wd1  = (const float*)d_in[1];
    const float* bd1  = (const float*)d_in[2];
    const float* Wd2  = (const float*)d_in[3];
    const float* bd2  = (const float*)d_in[4];
    const float* Wdo  = (const float*)d_in[5];
    const float* bdo  = (const float*)d_in[6];
    const float* Wo1  = (const float*)d_in[7];
    const float* bo1  = (const float*)d_in[8];
    const float* Wo2  = (const float*)d_in[9];
    const float* bo2  = (const float*)d_in[10];
    const float* Woo  = (const float*)d_in[11];
    const float* boo  = (const float*)d_in[12];
    const float* dmin = (const float*)d_in[13];
    float* out = (float*)d_out;

    // ws (ushorts): frags 753,664 us (1,507,328 B) + boo_p8 2240 f32 (8,960 B)
    ushort* ws   = (ushort*)d_ws;
    ushort* wd1f = ws;                      // octets [0, 2048)
    ushort* wo1f = ws + 2048 * 8;           // [2048, 4096)
    ushort* wd2f = ws + 4096 * 8;           // [4096, 12288)
    ushort* wo2f = ws + 12288 * 8;          // [12288, 20480)
    ushort* wdof = ws + 20480 * 8;          // [20480, 22528)
    ushort* woof = ws + 22528 * 8;          // [22528, 94208)
    float*  boo_p8 = (float*)(ws + 753664);

    pack_all<<<2953, 256, 0, stream>>>(Wd1, Wd2, Wdo, Wo1, Wo2, Woo, boo, ws, boo_p8);

    hipFuncSetAttribute((const void*)damping_fused,
                        hipFuncAttributeMaxDynamicSharedMemorySize, LDS_BYTES);

    damping_fused<<<32768 / BT, THREADS, LDS_BYTES, stream>>>(
        x, wd1f, wd2f, wdof, wo1f, wo2f, woof,
        bd1, bd2, bdo, bo1, bo2, boo_p8, dmin, out);
}